// Round 5
// baseline (238.997 us; speedup 1.0000x reference)
//
#include <hip/hip_runtime.h>
#include <math.h>

// MoE top-2 router. Round 8: barrier decoupled from VMEM.
// R7 still stalled ~70%: the per-chunk barrier drained W global_load_lds ops
// issued only ~200cy earlier (L2->LDS latency ~300-500cy), phase-locked.
// Fix: W fragments are PRIVATE per lane (8 contiguous bf16 of its expert row)
// -> load W direct to registers (R5-verified layout), double-named wA/wB
// rotation (16 VGPR/set, no R5 collapse). Only x (shared 4KB/chunk) goes
// through LDS, with R7's verified split-once convert + XOR swizzle, 2-deep
// reg staging. The barrier is preceded ONLY by lgkmcnt(0): no vmcnt drain
// anywhere in the k-loop. LDS 40KB -> 8KB.
//
// x: [16384, 2048] fp32, W: [64, 2048] fp32.
// outputs (concat, fp32): mask [T,64], idx-as-float [T,2],
//                         router_probs [T,64], probs [T,64]

#define D_DIM 2048
#define E_DIM 64
#define NCH   (D_DIM >> 6)   // 32 chunks of 64 k

typedef __bf16 bf16x8 __attribute__((ext_vector_type(8)));
typedef float f32x4 __attribute__((ext_vector_type(4)));

static __device__ __forceinline__ unsigned short f2bf(float f) {
    unsigned int u = __float_as_uint(f);
    u += 0x7fffu + ((u >> 16) & 1u);   // RNE
    return (unsigned short)(u >> 16);
}
static __device__ __forceinline__ float bf2f(unsigned short h) {
    return __uint_as_float(((unsigned int)h) << 16);
}
static __device__ __forceinline__ void split4(const float4 v, ushort4* h, ushort4* l) {
    h->x = f2bf(v.x); l->x = f2bf(v.x - bf2f(h->x));
    h->y = f2bf(v.y); l->y = f2bf(v.y - bf2f(h->y));
    h->z = f2bf(v.z); l->z = f2bf(v.z - bf2f(h->z));
    h->w = f2bf(v.w); l->w = f2bf(v.w - bf2f(h->w));
}

// ---- pre-convert W (64x2048 fp32) -> bf16 hi/lo, linear layout ----
__global__ __launch_bounds__(256, 1) void convert_w(
    const float4* __restrict__ W4, unsigned short* __restrict__ WH,
    unsigned short* __restrict__ WL)
{
    int i = blockIdx.x * 256 + threadIdx.x;   // float4 index
    float4 v = W4[i];
    ushort4 h, l;
    split4(v, &h, &l);
    *(ushort4*)&WH[i * 4] = h;
    *(ushort4*)&WL[i * 4] = l;
}

// W register set: B-fragments for 2 k-steps (hi/lo). 16 VGPRs.
struct WR { bf16x8 h0, h1, l0, l1; };

static __device__ __forceinline__ void ldwr(
    WR& w, const unsigned short* ph, const unsigned short* pl, int q8) {
    // k-step 0: octet q8/8; k-step 1: octet 4+q8/8  (elements)
    w.h0 = *(const bf16x8*)(ph + q8);
    w.h1 = *(const bf16x8*)(ph + 32 + q8);
    w.l0 = *(const bf16x8*)(pl + q8);
    w.l1 = *(const bf16x8*)(pl + 32 + q8);
}

// ---- fused GEMM + softmax + top-2 + outputs ----
// block = 16 tokens x 64 experts x K=2048; 256 threads (4 waves);
// wave wv computes expert tile [wv*16, wv*16+16) for all 16 tokens.
__global__ __launch_bounds__(256, 4) void router_fused(
    const float* __restrict__ x,
    const unsigned short* __restrict__ WHg, const unsigned short* __restrict__ WLg,
    float* __restrict__ mask_out, float* __restrict__ idx_out,
    float* __restrict__ rp_out, float* __restrict__ probs_out)
{
    // bf16 x tiles (hi/lo), XOR-swizzled at 16B-slot level (R7-verified).
    __shared__ __align__(16) unsigned short XH[2][16 * 64];  // 2x 2 KB
    __shared__ __align__(16) unsigned short XL[2][16 * 64];  // 2x 2 KB
    // total 8 KB

    const int tid  = threadIdx.x;
    const int lane = tid & 63;
    const int wv   = tid >> 6;
    const int quad = lane >> 4;
    const int l16  = lane & 15;

    const int t0 = blockIdx.x << 4;

    f32x4 acc = {0.f, 0.f, 0.f, 0.f};

    // x stage: thread loads float4 at row (t0+l16), k = kc + wv*16 + quad*4.
    const float* xg = x + (size_t)(t0 + l16) * D_DIM + wv * 16 + quad * 4;
    // ds_write byte offset (R7-verified): row l16, 8B granule g = wv*4+quad.
    const int g   = wv * 4 + quad;
    const int cwb = l16 * 128 + (((g >> 1) ^ (l16 & 7)) << 4) + (g & 1) * 8;

    // W direct: lane's expert row, hi/lo.
    const int e = wv * 16 + l16;
    const unsigned short* whp = WHg + (size_t)e * D_DIM;
    const unsigned short* wlp = WLg + (size_t)e * D_DIM;
    const int q8 = quad * 8;

    // A-frag read offsets (R7-verified swizzle), k-steps 0/1
    const int ab0 = l16 * 128 + ((( quad     ) ^ (l16 & 7)) << 4);
    const int ab1 = l16 * 128 + (((4 + quad  ) ^ (l16 & 7)) << 4);

#define CONVERT_WRITE(xv, b) do {                                  \
        ushort4 _h, _l;                                            \
        split4((xv), &_h, &_l);                                    \
        *(ushort4*)((char*)&XH[(b)][0] + cwb) = _h;                \
        *(ushort4*)((char*)&XL[(b)][0] + cwb) = _l;                \
    } while (0)

#define COMPUTE(b, w) do {                                                     \
        bf16x8 _ah0 = *(const bf16x8*)((const char*)&XH[(b)][0] + ab0);        \
        bf16x8 _al0 = *(const bf16x8*)((const char*)&XL[(b)][0] + ab0);        \
        acc = __builtin_amdgcn_mfma_f32_16x16x32_bf16(_ah0, (w).h0, acc, 0,0,0);\
        acc = __builtin_amdgcn_mfma_f32_16x16x32_bf16(_al0, (w).h0, acc, 0,0,0);\
        acc = __builtin_amdgcn_mfma_f32_16x16x32_bf16(_ah0, (w).l0, acc, 0,0,0);\
        bf16x8 _ah1 = *(const bf16x8*)((const char*)&XH[(b)][0] + ab1);        \
        bf16x8 _al1 = *(const bf16x8*)((const char*)&XL[(b)][0] + ab1);        \
        acc = __builtin_amdgcn_mfma_f32_16x16x32_bf16(_ah1, (w).h1, acc, 0,0,0);\
        acc = __builtin_amdgcn_mfma_f32_16x16x32_bf16(_al1, (w).h1, acc, 0,0,0);\
        acc = __builtin_amdgcn_mfma_f32_16x16x32_bf16(_ah1, (w).l1, acc, 0,0,0);\
    } while (0)

#define PUBLISH() do {                                   \
        asm volatile("s_waitcnt lgkmcnt(0)" ::: "memory");\
        __builtin_amdgcn_sched_barrier(0);               \
        __builtin_amdgcn_s_barrier();                    \
        __builtin_amdgcn_sched_barrier(0);               \
    } while (0)

    WR wA, wB;
    float4 xa, xb;

    // ---- prologue ----
    {
        float4 x0v = *(const float4*)(xg);        // x(0)
        ldwr(wA, whp, wlp, q8);                   // W(0) -> wA
        xa = *(const float4*)(xg + 64);           // x(1)
        CONVERT_WRITE(x0v, 0);                    // (waits x0v only)
        PUBLISH();                                // X(0) visible; W/x stay in flight
    }

    // ---- main loop: even uses wA, odd uses wB; converts alternate xa/xb ----
    for (int ch = 0; ch < NCH; ch += 2) {
        // ---- even chunk ch ----
        if (ch + 2 < NCH) xb = *(const float4*)(xg + (ch + 2) * 64); // x(ch+2)
        if (ch + 1 < NCH) ldwr(wB, whp + (ch + 1) * 64, wlp + (ch + 1) * 64, q8);
        COMPUTE(ch & 1, wA);
        if (ch + 1 < NCH) {
            CONVERT_WRITE(xa, (ch + 1) & 1);      // xa = x(ch+1), 1 iter old
            PUBLISH();
        }

        // ---- odd chunk ch+1 ----
        const int co = ch + 1;
        if (co + 2 < NCH) xa = *(const float4*)(xg + (co + 2) * 64); // x(co+2)
        if (co + 1 < NCH) ldwr(wA, whp + (co + 1) * 64, wlp + (co + 1) * 64, q8);
        COMPUTE(co & 1, wB);
        if (co + 1 < NCH) {
            CONVERT_WRITE(xb, (co + 1) & 1);      // xb = x(co+1), 1 iter old
            PUBLISH();
        }
    }

    // ---- epilogue: exchange 16-expert slices via LDS, then 64-lane reduce ----
    // acc[r] = logit(token = quad*4 + r, expert = wv*16 + l16).
    __syncthreads();                              // all compute done; reuse XH
    float* L = (float*)&XH[0][0];                 // 4 KB = [16 tokens][64 experts]
    #pragma unroll
    for (int r = 0; r < 4; ++r)
        L[(quad * 4 + r) * 64 + wv * 16 + l16] = acc[r];
    __syncthreads();

    for (int i = 0; i < 4; ++i) {
        const int tl = wv * 4 + i;             // token within block
        const int t  = t0 + tl;
        const float v = L[tl * 64 + lane];

        // argmax, lower-index tie-break (matches jax.lax.top_k)
        float bv = v; int bi = lane;
        #pragma unroll
        for (int off = 1; off < 64; off <<= 1) {
            float ov = __shfl_xor(bv, off, 64);
            int   oi = __shfl_xor(bi, off, 64);
            bool take = (ov > bv) || (ov == bv && oi < bi);
            bv = take ? ov : bv;
            bi = take ? oi : bi;
        }
        const float m = bv; const int i1 = bi;

        const float p = __expf(v - m);
        float s = p;
        #pragma unroll
        for (int off = 1; off < 64; off <<= 1) s += __shfl_xor(s, off, 64);
        const float prob = p / s;

        // second argmax excluding i1
        const float v2 = (lane == i1) ? -INFINITY : v;
        float cv = v2; int ci = lane;
        #pragma unroll
        for (int off = 1; off < 64; off <<= 1) {
            float ov = __shfl_xor(cv, off, 64);
            int   oi = __shfl_xor(ci, off, 64);
            bool take = (ov > cv) || (ov == cv && oi < ci);
            cv = take ? ov : cv;
            ci = take ? oi : ci;
        }
        const int i2 = ci;

        const float pd = __shfl(prob, i1, 64) + __shfl(prob, i2, 64);
        const bool top = (lane == i1) || (lane == i2);

        const size_t base = (size_t)t * 64 + lane;
        mask_out[base]  = top ? 1.f : 0.f;
        rp_out[base]    = top ? prob / pd : 0.f;
        probs_out[base] = prob;
        if (lane == 0) {
            idx_out[(size_t)t * 2]     = (float)i1;
            idx_out[(size_t)t * 2 + 1] = (float)i2;
        }
    }
#undef CONVERT_WRITE
#undef COMPUTE
#undef PUBLISH
}

extern "C" void kernel_launch(void* const* d_in, const int* in_sizes, int n_in,
                              void* d_out, int out_size, void* d_ws, size_t ws_size,
                              hipStream_t stream) {
    const float* x = (const float*)d_in[0];
    const float* W = (const float*)d_in[1];
    float* out = (float*)d_out;

    const int T  = in_sizes[0] / D_DIM;     // 16384 tokens
    const int WN = in_sizes[1];             // 131072 elements

    unsigned short* WH = (unsigned short*)d_ws;
    unsigned short* WL = WH + WN;           // total ws use: 512 KB

    float* mask_out  = out;
    float* idx_out   = out + (size_t)T * E_DIM;
    float* rp_out    = idx_out + (size_t)T * 2;
    float* probs_out = rp_out + (size_t)T * E_DIM;

    convert_w<<<dim3(WN / 1024), dim3(256), 0, stream>>>((const float4*)W, WH, WL);
    router_fused<<<dim3(T / 16), dim3(256), 0, stream>>>(
        x, WH, WL, mask_out, idx_out, rp_out, probs_out);
}